// Round 1
// baseline (595.967 us; speedup 1.0000x reference)
//
#include <hip/hip_runtime.h>
#include <math.h>

#define Bn 8
#define Cn 512
#define Tn 1024
#define Gn 32
#define CPG 16
#define NH 8
#define CHn 64

// ---------------------------------------------------------------------------
// GroupNorm: one block per (b, group). 16 channels x 1024 = 16384 elements.
// ---------------------------------------------------------------------------
__global__ __launch_bounds__(256) void gn_kernel(const float* __restrict__ x,
                                                 const float* __restrict__ gw,
                                                 const float* __restrict__ gb,
                                                 float* __restrict__ xn) {
  const int blk = blockIdx.x;           // b*32 + g
  const int b = blk >> 5, g = blk & 31;
  const size_t base = ((size_t)b * Cn + (size_t)g * CPG) * Tn;
  const float4* __restrict__ xin = (const float4*)(x + base);
  float4* __restrict__ xno = (float4*)(xn + base);
  const int tid = threadIdx.x;

  float4 v[16];
  float sum = 0.f, sq = 0.f;
#pragma unroll
  for (int k = 0; k < 16; ++k) {
    v[k] = xin[tid + (k << 8)];
    sum += v[k].x + v[k].y + v[k].z + v[k].w;
    sq += v[k].x * v[k].x + v[k].y * v[k].y + v[k].z * v[k].z + v[k].w * v[k].w;
  }

  __shared__ float rs[8];
  const int lane = tid & 63, wv = tid >> 6;
#pragma unroll
  for (int off = 32; off > 0; off >>= 1) {
    sum += __shfl_down(sum, off);
    sq += __shfl_down(sq, off);
  }
  if (lane == 0) { rs[wv] = sum; rs[4 + wv] = sq; }
  __syncthreads();
  const float ts = rs[0] + rs[1] + rs[2] + rs[3];
  const float tq = rs[4] + rs[5] + rs[6] + rs[7];
  const float mean = ts * (1.f / 16384.f);
  const float var = tq * (1.f / 16384.f) - mean * mean;
  const float rstd = rsqrtf(var + 1e-5f);

#pragma unroll
  for (int k = 0; k < 16; ++k) {
    // thread's k-th float4 lives in channel (g*16 + k), position tid*4
    const float a = rstd * gw[g * CPG + k];
    const float bb = gb[g * CPG + k];
    float4 o;
    o.x = (v[k].x - mean) * a + bb;
    o.y = (v[k].y - mean) * a + bb;
    o.z = (v[k].z - mean) * a + bb;
    o.w = (v[k].w - mean) * a + bb;
    xno[tid + (k << 8)] = o;
  }
}

// ---------------------------------------------------------------------------
// Tiled fp32 GEMM: out[b,o,t] = sum_c W[o,c] * X[b,c,t] + bias[o] (+ resid)
// 64x64 tile, BK=16, 256 threads, 4x4 micro-tile.
// ---------------------------------------------------------------------------
__global__ __launch_bounds__(256) void gemm_kernel(const float* __restrict__ W,
                                                   const float* __restrict__ X,
                                                   const float* __restrict__ bias,
                                                   const float* __restrict__ resid,
                                                   float* __restrict__ out, int M) {
  const int K = 512;
  const int o0 = blockIdx.x << 6, t0 = blockIdx.y << 6, b = blockIdx.z;
  const float* __restrict__ Xb = X + (size_t)b * K * Tn;
  __shared__ float Ws[16][68];
  __shared__ float Xs[16][68];
  const int tid = threadIdx.x;
  const int om = (tid >> 4) << 2;   // output-row offset in tile
  const int tn = (tid & 15) << 2;   // output-col offset in tile
  const int lw_row = tid >> 2;      // W row within tile
  const int lw_k = (tid & 3) << 2;  // W k-offset
  const int lx_k = tid >> 4;        // X k-row
  const int lx_t = (tid & 15) << 2; // X t-offset

  const float* wp = &W[(size_t)(o0 + lw_row) * K + lw_k];
  const float* xp = &Xb[(size_t)lx_k * Tn + t0 + lx_t];

  float acc[4][4] = {};
  for (int k0 = 0; k0 < K; k0 += 16) {
    const float4 w4 = *(const float4*)(wp + k0);
    const float4 x4 = *(const float4*)(xp + (size_t)k0 * Tn);
    Ws[lw_k + 0][lw_row] = w4.x;
    Ws[lw_k + 1][lw_row] = w4.y;
    Ws[lw_k + 2][lw_row] = w4.z;
    Ws[lw_k + 3][lw_row] = w4.w;
    *(float4*)&Xs[lx_k][lx_t] = x4;
    __syncthreads();
#pragma unroll
    for (int k = 0; k < 16; ++k) {
      const float4 a4 = *(const float4*)&Ws[k][om];
      const float4 b4 = *(const float4*)&Xs[k][tn];
      const float aa[4] = {a4.x, a4.y, a4.z, a4.w};
      const float bb[4] = {b4.x, b4.y, b4.z, b4.w};
#pragma unroll
      for (int i = 0; i < 4; ++i)
#pragma unroll
        for (int j = 0; j < 4; ++j) acc[i][j] = fmaf(aa[i], bb[j], acc[i][j]);
    }
    __syncthreads();
  }

#pragma unroll
  for (int i = 0; i < 4; ++i) {
    const int orow = o0 + om + i;
    const float bv = bias[orow];
    float4 r;
    r.x = acc[i][0] + bv;
    r.y = acc[i][1] + bv;
    r.z = acc[i][2] + bv;
    r.w = acc[i][3] + bv;
    if (resid) {
      const float4 rr = *(const float4*)&resid[((size_t)b * Cn + orow) * Tn + t0 + tn];
      r.x += rr.x; r.y += rr.y; r.z += rr.z; r.w += rr.w;
    }
    *(float4*)&out[((size_t)b * M + orow) * Tn + t0 + tn] = r;
  }
}

// ---------------------------------------------------------------------------
// Flash-style attention. One block per (head-batch hb, 64-row t-tile).
// qkv layout [B][1536][T]; head h uses rows h*192 (q), +64 (k), +128 (v).
// Output h[b, h*64+c, t] = sum_s softmax_s(q.k/8)[t,s] * v[c,s]
// ---------------------------------------------------------------------------
__global__ __launch_bounds__(256) void attn_kernel(const float* __restrict__ qkv,
                                                   float* __restrict__ hout) {
  const int tt = blockIdx.x, hb = blockIdx.y;
  const int b = hb >> 3, hh = hb & 7;
  const float* __restrict__ Qg = qkv + ((size_t)b * 1536 + hh * 192) * Tn;
  const float* __restrict__ Kg = Qg + (size_t)64 * Tn;
  const float* __restrict__ Vg = Qg + (size_t)128 * Tn;
  const int t0 = tt << 6;

  __shared__ float Qs[64][68];   // Q[c][t]
  __shared__ float KVs[64][68];  // K[c][s], then transposed V[s][c]
  __shared__ float Ss[64][68];   // S[t][s], then transposed P[s][t]
  __shared__ float alpha_s[64];
  __shared__ float l_s[64];

  const int tid = threadIdx.x;
  const int lc = tid >> 2, lp = tid & 3;          // loader mapping
  const int sct = (tid >> 4) << 2;                // micro-tile row (t for S; c for O)
  const int scs = (tid & 15) << 2;                // micro-tile col (s for S; t for O)
  const int smr = tid >> 2, sms = (tid & 3) << 4; // softmax row / col-start

  // load Q tile
#pragma unroll
  for (int j = 0; j < 4; ++j)
    *(float4*)&Qs[lc][lp * 16 + j * 4] =
        *(const float4*)&Qg[(size_t)lc * Tn + t0 + lp * 16 + j * 4];

  float acc[4][4] = {};
  float m_run = -1e30f, l_run = 0.f;

  for (int st = 0; st < 16; ++st) {
    const int s0 = st << 6;
    // load K tile (KVs written; prev iter's reads finished at loop-end barrier)
#pragma unroll
    for (int j = 0; j < 4; ++j)
      *(float4*)&KVs[lc][lp * 16 + j * 4] =
          *(const float4*)&Kg[(size_t)lc * Tn + s0 + lp * 16 + j * 4];
    __syncthreads();

    // S[t][s] = 0.125 * sum_c Q[c][t] K[c][s]
    float sacc[4][4] = {};
#pragma unroll 8
    for (int c = 0; c < 64; ++c) {
      const float4 q4 = *(const float4*)&Qs[c][sct];
      const float4 k4 = *(const float4*)&KVs[c][scs];
      const float qa[4] = {q4.x, q4.y, q4.z, q4.w};
      const float ka[4] = {k4.x, k4.y, k4.z, k4.w};
#pragma unroll
      for (int i = 0; i < 4; ++i)
#pragma unroll
        for (int j = 0; j < 4; ++j) sacc[i][j] = fmaf(qa[i], ka[j], sacc[i][j]);
    }
#pragma unroll
    for (int i = 0; i < 4; ++i) {
      float4 o;
      o.x = sacc[i][0] * 0.125f;
      o.y = sacc[i][1] * 0.125f;
      o.z = sacc[i][2] * 0.125f;
      o.w = sacc[i][3] * 0.125f;
      *(float4*)&Ss[sct + i][scs] = o;
    }
    __syncthreads();

    // prefetch V tile into registers (hides under softmax)
    float4 vreg[4];
#pragma unroll
    for (int j = 0; j < 4; ++j)
      vreg[j] = *(const float4*)&Vg[(size_t)lc * Tn + s0 + lp * 16 + j * 4];

    // online softmax: row smr, cols [sms, sms+16); 4 lanes per row
    float p[16], mx = -1e30f;
#pragma unroll
    for (int j = 0; j < 16; ++j) {
      p[j] = Ss[smr][sms + j];
      mx = fmaxf(mx, p[j]);
    }
    mx = fmaxf(mx, __shfl_xor(mx, 1));
    mx = fmaxf(mx, __shfl_xor(mx, 2));
    const float m_new = fmaxf(m_run, mx);
    const float alpha = __expf(m_run - m_new);
    float ls = 0.f;
#pragma unroll
    for (int j = 0; j < 16; ++j) {
      p[j] = __expf(p[j] - m_new);
      ls += p[j];
    }
    ls += __shfl_xor(ls, 1);
    ls += __shfl_xor(ls, 2);
    l_run = l_run * alpha + ls;
    m_run = m_new;
    if ((tid & 3) == 0) { alpha_s[smr] = alpha; l_s[smr] = l_run; }
    __syncthreads();  // all Ss reads done before transpose-overwrite

    // transpose P into Ss (Pt[s][t]) and V into KVs (Vt[s][c])
#pragma unroll
    for (int j = 0; j < 16; ++j) Ss[sms + j][smr] = p[j];
#pragma unroll
    for (int j = 0; j < 4; ++j) {
      KVs[lp * 16 + j * 4 + 0][lc] = vreg[j].x;
      KVs[lp * 16 + j * 4 + 1][lc] = vreg[j].y;
      KVs[lp * 16 + j * 4 + 2][lc] = vreg[j].z;
      KVs[lp * 16 + j * 4 + 3][lc] = vreg[j].w;
    }
    __syncthreads();

    // O[c][t] = O*alpha(t) + sum_s Vt[s][c] * Pt[s][t]
    float av[4];
#pragma unroll
    for (int j = 0; j < 4; ++j) av[j] = alpha_s[scs + j];
#pragma unroll
    for (int i = 0; i < 4; ++i)
#pragma unroll
      for (int j = 0; j < 4; ++j) acc[i][j] *= av[j];
#pragma unroll 8
    for (int s = 0; s < 64; ++s) {
      const float4 v4 = *(const float4*)&KVs[s][sct];
      const float4 p4 = *(const float4*)&Ss[s][scs];
      const float va[4] = {v4.x, v4.y, v4.z, v4.w};
      const float pa[4] = {p4.x, p4.y, p4.z, p4.w};
#pragma unroll
      for (int i = 0; i < 4; ++i)
#pragma unroll
        for (int j = 0; j < 4; ++j) acc[i][j] = fmaf(va[i], pa[j], acc[i][j]);
    }
    __syncthreads();  // before next K-tile overwrites KVs
  }

  // epilogue: divide by l and store h[b, hh*64 + c, t0 + t]
  float rl[4];
#pragma unroll
  for (int j = 0; j < 4; ++j) rl[j] = 1.f / l_s[scs + j];
  float* __restrict__ Hg = hout + ((size_t)b * Cn + hh * CHn) * Tn;
#pragma unroll
  for (int i = 0; i < 4; ++i) {
    float4 o;
    o.x = acc[i][0] * rl[0];
    o.y = acc[i][1] * rl[1];
    o.z = acc[i][2] * rl[2];
    o.w = acc[i][3] * rl[3];
    *(float4*)&Hg[(size_t)(sct + i) * Tn + t0 + scs] = o;
  }
}

// ---------------------------------------------------------------------------
extern "C" void kernel_launch(void* const* d_in, const int* in_sizes, int n_in,
                              void* d_out, int out_size, void* d_ws, size_t ws_size,
                              hipStream_t stream) {
  (void)in_sizes; (void)n_in; (void)out_size; (void)ws_size;
  const float* x = (const float*)d_in[0];
  const float* gn_w = (const float*)d_in[1];
  const float* gn_b = (const float*)d_in[2];
  const float* qkv_w = (const float*)d_in[3];
  const float* qkv_b = (const float*)d_in[4];
  const float* proj_w = (const float*)d_in[5];
  const float* proj_b = (const float*)d_in[6];
  float* out = (float*)d_out;

  float* xn = (float*)d_ws;                       // [8][512][1024]  (16 MB)
  float* qkv = xn + (size_t)Bn * Cn * Tn;         // [8][1536][1024] (48 MB)

  // 1. GroupNorm -> xn
  gn_kernel<<<dim3(Bn * Gn), 256, 0, stream>>>(x, gn_w, gn_b, xn);
  // 2. QKV GEMM: [1536,512] x xn -> qkv
  gemm_kernel<<<dim3(24, 16, Bn), 256, 0, stream>>>(qkv_w, xn, qkv_b, nullptr, qkv, 1536);
  // 3. Attention -> h (overwrites xn; xn is dead after step 2)
  attn_kernel<<<dim3(16, 64), 256, 0, stream>>>(qkv, xn);
  // 4. Proj GEMM + bias + residual(x) -> out
  gemm_kernel<<<dim3(8, 16, Bn), 256, 0, stream>>>(proj_w, xn, proj_b, x, out, 512);
}

// Round 2
// 271.204 us; speedup vs baseline: 2.1975x; 2.1975x over previous
//
#include <hip/hip_runtime.h>
#include <math.h>

#define Bn 8
#define Cn 512
#define Tn 1024

typedef __attribute__((ext_vector_type(8))) short bf16x8;
typedef __attribute__((ext_vector_type(4))) float f32x4;

__device__ __forceinline__ unsigned short f2bf(float f) {
  unsigned int u = __builtin_bit_cast(unsigned int, f);
  u = (u + 0x7FFFu + ((u >> 16) & 1u)) >> 16;
  return (unsigned short)u;
}

// ---------------------------------------------------------------------------
// GroupNorm -> bf16 transposed xn_t [b][t][c]
// block = (b, g): 16 channels x 1024 positions
// ---------------------------------------------------------------------------
__global__ __launch_bounds__(256) void gn_kernel(const float* __restrict__ x,
                                                 const float* __restrict__ gw,
                                                 const float* __restrict__ gb,
                                                 unsigned short* __restrict__ xn_t) {
  const int blk = blockIdx.x;
  const int b = blk >> 5, g = blk & 31;
  const size_t base = ((size_t)b * Cn + (size_t)g * 16) * Tn;
  const float4* __restrict__ xin = (const float4*)(x + base);
  const int tid = threadIdx.x;

  float vv[16][4];
  float sum = 0.f, sq = 0.f;
#pragma unroll
  for (int k = 0; k < 16; ++k) {
    const float4 t4 = xin[tid + (k << 8)];
    vv[k][0] = t4.x; vv[k][1] = t4.y; vv[k][2] = t4.z; vv[k][3] = t4.w;
    sum += t4.x + t4.y + t4.z + t4.w;
    sq += t4.x * t4.x + t4.y * t4.y + t4.z * t4.z + t4.w * t4.w;
  }

  __shared__ float rs[8];
  const int lane = tid & 63, wv = tid >> 6;
#pragma unroll
  for (int off = 32; off > 0; off >>= 1) {
    sum += __shfl_down(sum, off);
    sq += __shfl_down(sq, off);
  }
  if (lane == 0) { rs[wv] = sum; rs[4 + wv] = sq; }
  __syncthreads();
  const float ts = rs[0] + rs[1] + rs[2] + rs[3];
  const float tq = rs[4] + rs[5] + rs[6] + rs[7];
  const float mean = ts * (1.f / 16384.f);
  const float var = tq * (1.f / 16384.f) - mean * mean;
  const float rstd = rsqrtf(var + 1e-5f);

  float aa[16], bb[16];
#pragma unroll
  for (int k = 0; k < 16; ++k) {
    aa[k] = rstd * gw[g * 16 + k];
    bb[k] = gb[g * 16 + k] - mean * aa[k];
  }

#pragma unroll
  for (int j = 0; j < 4; ++j) {
    const int t = tid * 4 + j;
    unsigned int pk[8];
#pragma unroll
    for (int k2 = 0; k2 < 8; ++k2) {
      const unsigned int lo = f2bf(vv[2 * k2][j] * aa[2 * k2] + bb[2 * k2]);
      const unsigned int hi = f2bf(vv[2 * k2 + 1][j] * aa[2 * k2 + 1] + bb[2 * k2 + 1]);
      pk[k2] = lo | (hi << 16);
    }
    unsigned short* dst = xn_t + ((size_t)(b * Tn + t)) * Cn + g * 16;
    *(uint4*)dst = make_uint4(pk[0], pk[1], pk[2], pk[3]);
    *((uint4*)dst + 1) = make_uint4(pk[4], pk[5], pk[6], pk[7]);
  }
}

// ---------------------------------------------------------------------------
// fp32 -> bf16 convert (weights)
// ---------------------------------------------------------------------------
__global__ __launch_bounds__(256) void cvt_kernel(const float* __restrict__ src,
                                                  unsigned short* __restrict__ dst, int n4) {
  const int i = blockIdx.x * 256 + threadIdx.x;
  if (i < n4) {
    const float4 f = ((const float4*)src)[i];
    uint2 o;
    o.x = (unsigned int)f2bf(f.x) | ((unsigned int)f2bf(f.y) << 16);
    o.y = (unsigned int)f2bf(f.z) | ((unsigned int)f2bf(f.w) << 16);
    ((uint2*)dst)[i] = o;
  }
}

// ---------------------------------------------------------------------------
// QKV GEMM: D[o,t] = sum_c W[o,c] * xn_t[t,c], +bias, scatter to q/k/v layouts
// grid (12, 8, 8); 128x128 tile; wave w -> 64x64 sub-tile; 16x16x32 MFMA
// q_t,k_t: [bh][t][64]   v_t: [bh][c][1024]
// ---------------------------------------------------------------------------
__global__ __launch_bounds__(256, 2) void qkv_gemm(const unsigned short* __restrict__ Wb,
                                                   const unsigned short* __restrict__ Xb,
                                                   const float* __restrict__ bias,
                                                   unsigned short* __restrict__ q_t,
                                                   unsigned short* __restrict__ k_t,
                                                   unsigned short* __restrict__ v_t) {
  const int tid = threadIdx.x, lane = tid & 63, w = tid >> 6;
  const int wr = w >> 1, wc = w & 1;
  const int o_base = blockIdx.x * 128 + wr * 64;
  const int t_base = blockIdx.y * 128 + wc * 64;
  const int b = blockIdx.z;
  const int ln = lane & 15, g8 = (lane >> 4) * 8;
  const unsigned short* __restrict__ X = Xb + (size_t)b * Tn * Cn;

  const unsigned short* ap[4];
  const unsigned short* bp[4];
#pragma unroll
  for (int mt = 0; mt < 4; ++mt) ap[mt] = Wb + (size_t)(o_base + mt * 16 + ln) * 512 + g8;
#pragma unroll
  for (int nt = 0; nt < 4; ++nt) bp[nt] = X + (size_t)(t_base + nt * 16 + ln) * 512 + g8;

  f32x4 acc[4][4];
#pragma unroll
  for (int mt = 0; mt < 4; ++mt)
#pragma unroll
    for (int nt = 0; nt < 4; ++nt) acc[mt][nt] = (f32x4){0.f, 0.f, 0.f, 0.f};

#pragma unroll 2
  for (int k0 = 0; k0 < 512; k0 += 32) {
    bf16x8 af[4], bf[4];
#pragma unroll
    for (int mt = 0; mt < 4; ++mt) af[mt] = *(const bf16x8*)(ap[mt] + k0);
#pragma unroll
    for (int nt = 0; nt < 4; ++nt) bf[nt] = *(const bf16x8*)(bp[nt] + k0);
#pragma unroll
    for (int mt = 0; mt < 4; ++mt)
#pragma unroll
      for (int nt = 0; nt < 4; ++nt)
        acc[mt][nt] = __builtin_amdgcn_mfma_f32_16x16x32_bf16(af[mt], bf[nt], acc[mt][nt], 0, 0, 0);
  }

#pragma unroll
  for (int mt = 0; mt < 4; ++mt) {
    const int ob16 = o_base + mt * 16;
    const int part = (ob16 >> 6) % 3;
    const int hh = ob16 / 192;
    const int c16 = ob16 & 63;
    const int bh = b * 8 + hh;
    float bv[4];
#pragma unroll
    for (int r = 0; r < 4; ++r) bv[r] = bias[ob16 + (lane >> 4) * 4 + r];
#pragma unroll
    for (int nt = 0; nt < 4; ++nt) {
      const int t = t_base + nt * 16 + ln;
      const float v0 = acc[mt][nt][0] + bv[0];
      const float v1 = acc[mt][nt][1] + bv[1];
      const float v2 = acc[mt][nt][2] + bv[2];
      const float v3 = acc[mt][nt][3] + bv[3];
      if (part < 2) {
        unsigned short* dst = (part == 0 ? q_t : k_t) + (size_t)bh * 65536 + (size_t)t * 64 +
                              c16 + (lane >> 4) * 4;
        uint2 pk;
        pk.x = (unsigned int)f2bf(v0) | ((unsigned int)f2bf(v1) << 16);
        pk.y = (unsigned int)f2bf(v2) | ((unsigned int)f2bf(v3) << 16);
        *(uint2*)dst = pk;
      } else {
        unsigned short* dst = v_t + (size_t)bh * 65536 + (size_t)(c16 + (lane >> 4) * 4) * Tn + t;
        dst[0] = f2bf(v0);
        dst[1024] = f2bf(v1);
        dst[2048] = f2bf(v2);
        dst[3072] = f2bf(v3);
      }
    }
  }
}

// ---------------------------------------------------------------------------
// Flash attention, MFMA. grid (8, 64): block = (t-chunk of 128, bh).
// 4 waves, each owns 32 t-rows. Q,K: [bh][t][64]; V: [bh][c][1024].
// Output h_t bf16 [b][t][512] (channel = hh*64 + c).
// ---------------------------------------------------------------------------
__global__ __launch_bounds__(256, 2) void attn_kernel(const unsigned short* __restrict__ q_t,
                                                      const unsigned short* __restrict__ k_t,
                                                      const unsigned short* __restrict__ v_t,
                                                      unsigned short* __restrict__ h_t) {
  __shared__ unsigned short P_lds[4][32][72];
  const int tid = threadIdx.x, lane = tid & 63, w = tid >> 6;
  const int bh = blockIdx.y;
  const int t_wave = blockIdx.x * 128 + w * 32;
  const int ln = lane & 15, g8 = (lane >> 4) * 8;
  const unsigned short* __restrict__ qbase = q_t + (size_t)bh * 65536;
  const unsigned short* __restrict__ kbase = k_t + (size_t)bh * 65536;
  const unsigned short* __restrict__ vbase = v_t + (size_t)bh * 65536;

  bf16x8 qf[2][2];
#pragma unroll
  for (int mt = 0; mt < 2; ++mt)
#pragma unroll
    for (int kb = 0; kb < 2; ++kb)
      qf[mt][kb] = *(const bf16x8*)(qbase + (size_t)(t_wave + mt * 16 + ln) * 64 + kb * 32 + g8);

  f32x4 o_acc[2][4];
  float m_run[2][4], l_run[2][4];
#pragma unroll
  for (int mt = 0; mt < 2; ++mt) {
#pragma unroll
    for (int nc = 0; nc < 4; ++nc) o_acc[mt][nc] = (f32x4){0.f, 0.f, 0.f, 0.f};
#pragma unroll
    for (int r = 0; r < 4; ++r) { m_run[mt][r] = -1e30f; l_run[mt][r] = 0.f; }
  }

  for (int st = 0; st < 16; ++st) {
    const int s0 = st << 6;
    f32x4 sacc[2][4];
#pragma unroll
    for (int mt = 0; mt < 2; ++mt)
#pragma unroll
      for (int ns = 0; ns < 4; ++ns) sacc[mt][ns] = (f32x4){0.f, 0.f, 0.f, 0.f};

#pragma unroll
    for (int ns = 0; ns < 4; ++ns)
#pragma unroll
      for (int kb = 0; kb < 2; ++kb) {
        const bf16x8 kf = *(const bf16x8*)(kbase + (size_t)(s0 + ns * 16 + ln) * 64 + kb * 32 + g8);
        sacc[0][ns] = __builtin_amdgcn_mfma_f32_16x16x32_bf16(qf[0][kb], kf, sacc[0][ns], 0, 0, 0);
        sacc[1][ns] = __builtin_amdgcn_mfma_f32_16x16x32_bf16(qf[1][kb], kf, sacc[1][ns], 0, 0, 0);
      }

    // online softmax; row t = mt*16 + (lane>>4)*4 + r, col s = ns*16 + ln
#pragma unroll
    for (int mt = 0; mt < 2; ++mt)
#pragma unroll
      for (int r = 0; r < 4; ++r) {
        float mx = fmaxf(fmaxf(sacc[mt][0][r], sacc[mt][1][r]),
                         fmaxf(sacc[mt][2][r], sacc[mt][3][r]));
        mx = fmaxf(mx, __shfl_xor(mx, 1));
        mx = fmaxf(mx, __shfl_xor(mx, 2));
        mx = fmaxf(mx, __shfl_xor(mx, 4));
        mx = fmaxf(mx, __shfl_xor(mx, 8));
        mx *= 0.125f;
        const float mold = m_run[mt][r];
        const float mnew = fmaxf(mold, mx);
        const float al = __expf(mold - mnew);
        m_run[mt][r] = mnew;
        float rsum = 0.f;
        const int trow = mt * 16 + (lane >> 4) * 4 + r;
#pragma unroll
        for (int ns = 0; ns < 4; ++ns) {
          const float pv = __expf(fmaf(sacc[mt][ns][r], 0.125f, -mnew));
          rsum += pv;
          P_lds[w][trow][ns * 16 + ln] = f2bf(pv);
        }
        rsum += __shfl_xor(rsum, 1);
        rsum += __shfl_xor(rsum, 2);
        rsum += __shfl_xor(rsum, 4);
        rsum += __shfl_xor(rsum, 8);
        l_run[mt][r] = l_run[mt][r] * al + rsum;
#pragma unroll
        for (int nc = 0; nc < 4; ++nc) o_acc[mt][nc][r] *= al;
      }

    bf16x8 pf[2][2];
#pragma unroll
    for (int mt = 0; mt < 2; ++mt)
#pragma unroll
      for (int kb = 0; kb < 2; ++kb)
        pf[mt][kb] = *(const bf16x8*)&P_lds[w][mt * 16 + ln][kb * 32 + g8];

#pragma unroll
    for (int kb = 0; kb < 2; ++kb)
#pragma unroll
      for (int nc = 0; nc < 4; ++nc) {
        const bf16x8 vf =
            *(const bf16x8*)(vbase + (size_t)(nc * 16 + ln) * Tn + s0 + kb * 32 + g8);
        o_acc[0][nc] = __builtin_amdgcn_mfma_f32_16x16x32_bf16(pf[0][kb], vf, o_acc[0][nc], 0, 0, 0);
        o_acc[1][nc] = __builtin_amdgcn_mfma_f32_16x16x32_bf16(pf[1][kb], vf, o_acc[1][nc], 0, 0, 0);
      }
  }

  // epilogue: O /= l, store bf16 to h_t[b][t][hh*64 + c]
  const int b = bh >> 3, hh = bh & 7;
  unsigned short* __restrict__ hb = h_t + (size_t)b * Tn * Cn + hh * 64;
#pragma unroll
  for (int mt = 0; mt < 2; ++mt) {
    float rl[4];
#pragma unroll
    for (int r = 0; r < 4; ++r) rl[r] = 1.f / l_run[mt][r];
#pragma unroll
    for (int nc = 0; nc < 4; ++nc) {
      const int c = nc * 16 + ln;
#pragma unroll
      for (int r = 0; r < 4; ++r) {
        const int t = t_wave + mt * 16 + (lane >> 4) * 4 + r;
        hb[(size_t)t * Cn + c] = f2bf(o_acc[mt][nc][r] * rl[r]);
      }
    }
  }
}

// ---------------------------------------------------------------------------
// Proj GEMM + bias + residual: out[b,o,t] = sum_c W[o,c]*h_t[t,c] + pb[o] + x
// grid (4, 8, 8)
// ---------------------------------------------------------------------------
__global__ __launch_bounds__(256, 2) void proj_gemm(const unsigned short* __restrict__ Wb,
                                                    const unsigned short* __restrict__ Hb,
                                                    const float* __restrict__ pbias,
                                                    const float* __restrict__ x,
                                                    float* __restrict__ out) {
  const int tid = threadIdx.x, lane = tid & 63, w = tid >> 6;
  const int wr = w >> 1, wc = w & 1;
  const int o_base = blockIdx.x * 128 + wr * 64;
  const int t_base = blockIdx.y * 128 + wc * 64;
  const int b = blockIdx.z;
  const int ln = lane & 15, g8 = (lane >> 4) * 8;
  const unsigned short* __restrict__ H = Hb + (size_t)b * Tn * Cn;

  const unsigned short* ap[4];
  const unsigned short* bp[4];
#pragma unroll
  for (int mt = 0; mt < 4; ++mt) ap[mt] = Wb + (size_t)(o_base + mt * 16 + ln) * 512 + g8;
#pragma unroll
  for (int nt = 0; nt < 4; ++nt) bp[nt] = H + (size_t)(t_base + nt * 16 + ln) * 512 + g8;

  f32x4 acc[4][4];
#pragma unroll
  for (int mt = 0; mt < 4; ++mt)
#pragma unroll
    for (int nt = 0; nt < 4; ++nt) acc[mt][nt] = (f32x4){0.f, 0.f, 0.f, 0.f};

#pragma unroll 2
  for (int k0 = 0; k0 < 512; k0 += 32) {
    bf16x8 af[4], bf[4];
#pragma unroll
    for (int mt = 0; mt < 4; ++mt) af[mt] = *(const bf16x8*)(ap[mt] + k0);
#pragma unroll
    for (int nt = 0; nt < 4; ++nt) bf[nt] = *(const bf16x8*)(bp[nt] + k0);
#pragma unroll
    for (int mt = 0; mt < 4; ++mt)
#pragma unroll
      for (int nt = 0; nt < 4; ++nt)
        acc[mt][nt] = __builtin_amdgcn_mfma_f32_16x16x32_bf16(af[mt], bf[nt], acc[mt][nt], 0, 0, 0);
  }

#pragma unroll
  for (int mt = 0; mt < 4; ++mt) {
    const int ob = o_base + mt * 16 + (lane >> 4) * 4;
    float pb[4];
#pragma unroll
    for (int r = 0; r < 4; ++r) pb[r] = pbias[ob + r];
#pragma unroll
    for (int nt = 0; nt < 4; ++nt) {
      const int t = t_base + nt * 16 + ln;
#pragma unroll
      for (int r = 0; r < 4; ++r) {
        const size_t idx = (size_t)b * Cn * Tn + (size_t)(ob + r) * Tn + t;
        out[idx] = acc[mt][nt][r] + pb[r] + x[idx];
      }
    }
  }
}

// ---------------------------------------------------------------------------
extern "C" void kernel_launch(void* const* d_in, const int* in_sizes, int n_in,
                              void* d_out, int out_size, void* d_ws, size_t ws_size,
                              hipStream_t stream) {
  (void)in_sizes; (void)n_in; (void)out_size; (void)ws_size;
  const float* x = (const float*)d_in[0];
  const float* gn_w = (const float*)d_in[1];
  const float* gn_b = (const float*)d_in[2];
  const float* qkv_w = (const float*)d_in[3];
  const float* qkv_b = (const float*)d_in[4];
  const float* proj_w = (const float*)d_in[5];
  const float* proj_b = (const float*)d_in[6];
  float* out = (float*)d_out;

  unsigned short* wsu = (unsigned short*)d_ws;
  unsigned short* xn_t = wsu;                         // [8][1024][512]   4M
  unsigned short* wqkv = xn_t + (size_t)4194304;      // [1536][512]      768K
  unsigned short* wproj = wqkv + (size_t)786432;      // [512][512]       256K
  unsigned short* q_t = wproj + (size_t)262144;       // [64][1024][64]   4M
  unsigned short* k_t = q_t + (size_t)4194304;        // 4M
  unsigned short* v_t = k_t + (size_t)4194304;        // [64][64][1024]   4M
  unsigned short* h_t = v_t + (size_t)4194304;        // [8][1024][512]   4M

  gn_kernel<<<dim3(256), 256, 0, stream>>>(x, gn_w, gn_b, xn_t);
  cvt_kernel<<<dim3(768), 256, 0, stream>>>(qkv_w, wqkv, 196608);
  cvt_kernel<<<dim3(256), 256, 0, stream>>>(proj_w, wproj, 65536);
  qkv_gemm<<<dim3(12, 8, 8), 256, 0, stream>>>(wqkv, xn_t, qkv_b, q_t, k_t, v_t);
  attn_kernel<<<dim3(8, 64), 256, 0, stream>>>(q_t, k_t, v_t, h_t);
  proj_gemm<<<dim3(4, 8, 8), 256, 0, stream>>>(wproj, h_t, proj_b, x, out);
}

// Round 4
// 181.295 us; speedup vs baseline: 3.2873x; 1.4959x over previous
//
#include <hip/hip_runtime.h>
#include <math.h>

#define Bn 8
#define Cn 512
#define Tn 1024

typedef __attribute__((ext_vector_type(8))) short bf16x8;
typedef __attribute__((ext_vector_type(4))) float f32x4;

__device__ __forceinline__ unsigned short f2bf(float f) {
  unsigned int u = __builtin_bit_cast(unsigned int, f);
  u = (u + 0x7FFFu + ((u >> 16) & 1u)) >> 16;
  return (unsigned short)u;
}

typedef __attribute__((address_space(1))) const unsigned int GU32;
typedef __attribute__((address_space(3))) unsigned int LU32;
__device__ __forceinline__ void gld16(const unsigned short* g, unsigned short* l) {
  __builtin_amdgcn_global_load_lds((GU32*)g, (LU32*)l, 16, 0, 0);
}

// Stage a 128-row x 64-col bf16 tile (rows x row_stride elements apart) into
// linear LDS [128][64] with XOR-swizzled columns: LDS[row][c16] holds
// G[row][c16 ^ (row&7)] (16B column units). 4 calls x 256 threads x 16B.
__device__ __forceinline__ void stage128x64(const unsigned short* __restrict__ src,
                                            size_t row_stride, unsigned short* lds, int tid) {
  const int w = tid >> 6;
  const int row = tid >> 3;                      // + c*32
  const int sc = (tid & 7) ^ ((tid >> 3) & 7);   // (c*32)&7 == 0, so row&7 == (tid>>3)&7
#pragma unroll
  for (int c = 0; c < 4; ++c)
    gld16(src + (size_t)(c * 32 + row) * row_stride + sc * 8,
          (unsigned short*)((char*)lds + c * 4096 + w * 1024));
}

// Same for a 64x64 tile (2 calls).
__device__ __forceinline__ void stage64x64(const unsigned short* __restrict__ src,
                                           size_t row_stride, unsigned short* lds, int tid) {
  const int w = tid >> 6;
  const int row = tid >> 3;
  const int sc = (tid & 7) ^ ((tid >> 3) & 7);
#pragma unroll
  for (int c = 0; c < 2; ++c)
    gld16(src + (size_t)(c * 32 + row) * row_stride + sc * 8,
          (unsigned short*)((char*)lds + c * 4096 + w * 1024));
}

// ---------------------------------------------------------------------------
// GroupNorm -> bf16 transposed xn_t [b][t][c]
// ---------------------------------------------------------------------------
__global__ __launch_bounds__(256) void gn_kernel(const float* __restrict__ x,
                                                 const float* __restrict__ gw,
                                                 const float* __restrict__ gb,
                                                 unsigned short* __restrict__ xn_t) {
  const int blk = blockIdx.x;
  const int b = blk >> 5, g = blk & 31;
  const size_t base = ((size_t)b * Cn + (size_t)g * 16) * Tn;
  const float4* __restrict__ xin = (const float4*)(x + base);
  const int tid = threadIdx.x;

  float vv[16][4];
  float sum = 0.f, sq = 0.f;
#pragma unroll
  for (int k = 0; k < 16; ++k) {
    const float4 t4 = xin[tid + (k << 8)];
    vv[k][0] = t4.x; vv[k][1] = t4.y; vv[k][2] = t4.z; vv[k][3] = t4.w;
    sum += t4.x + t4.y + t4.z + t4.w;
    sq += t4.x * t4.x + t4.y * t4.y + t4.z * t4.z + t4.w * t4.w;
  }

  __shared__ float rs[8];
  const int lane = tid & 63, wv = tid >> 6;
#pragma unroll
  for (int off = 32; off > 0; off >>= 1) {
    sum += __shfl_down(sum, off);
    sq += __shfl_down(sq, off);
  }
  if (lane == 0) { rs[wv] = sum; rs[4 + wv] = sq; }
  __syncthreads();
  const float ts = rs[0] + rs[1] + rs[2] + rs[3];
  const float tq = rs[4] + rs[5] + rs[6] + rs[7];
  const float mean = ts * (1.f / 16384.f);
  const float var = tq * (1.f / 16384.f) - mean * mean;
  const float rstd = rsqrtf(var + 1e-5f);

  float aa[16], bb[16];
#pragma unroll
  for (int k = 0; k < 16; ++k) {
    aa[k] = rstd * gw[g * 16 + k];
    bb[k] = gb[g * 16 + k] - mean * aa[k];
  }

#pragma unroll
  for (int j = 0; j < 4; ++j) {
    const int t = tid * 4 + j;
    unsigned int pk[8];
#pragma unroll
    for (int k2 = 0; k2 < 8; ++k2) {
      const unsigned int lo = f2bf(vv[2 * k2][j] * aa[2 * k2] + bb[2 * k2]);
      const unsigned int hi = f2bf(vv[2 * k2 + 1][j] * aa[2 * k2 + 1] + bb[2 * k2 + 1]);
      pk[k2] = lo | (hi << 16);
    }
    unsigned short* dst = xn_t + ((size_t)(b * Tn + t)) * Cn + g * 16;
    *(uint4*)dst = make_uint4(pk[0], pk[1], pk[2], pk[3]);
    *((uint4*)dst + 1) = make_uint4(pk[4], pk[5], pk[6], pk[7]);
  }
}

__global__ __launch_bounds__(256) void cvt_kernel(const float* __restrict__ src,
                                                  unsigned short* __restrict__ dst, int n4) {
  const int i = blockIdx.x * 256 + threadIdx.x;
  if (i < n4) {
    const float4 f = ((const float4*)src)[i];
    uint2 o;
    o.x = (unsigned int)f2bf(f.x) | ((unsigned int)f2bf(f.y) << 16);
    o.y = (unsigned int)f2bf(f.z) | ((unsigned int)f2bf(f.w) << 16);
    ((uint2*)dst)[i] = o;
  }
}

// ---------------------------------------------------------------------------
// QKV GEMM, LDS-staged 128x128 tile, BK=64 double-buffered. Flat grid 768,
// XCD-swizzled: b = id&7 (one batch image per XCD).
// ---------------------------------------------------------------------------
__global__ __launch_bounds__(256, 2) void qkv_gemm(const unsigned short* __restrict__ Wb,
                                                   const unsigned short* __restrict__ Xb,
                                                   const float* __restrict__ bias,
                                                   unsigned short* __restrict__ q_t,
                                                   unsigned short* __restrict__ k_t,
                                                   unsigned short* __restrict__ v_t) {
  __shared__ unsigned short As[2][8192];
  __shared__ unsigned short Bs[2][8192];
  const int id = blockIdx.x;
  const int b = id & 7;
  const int inner = id >> 3;           // 0..95
  const int bx = inner % 12, by = inner / 12;
  const int o0 = bx * 128, t0 = by * 128;
  const int tid = threadIdx.x, lane = tid & 63, w = tid >> 6;
  const int wr = w >> 1, wc = w & 1;
  const int ln = lane & 15, g16 = lane >> 4;
  const unsigned short* __restrict__ X = Xb + (size_t)b * Tn * Cn;
  const unsigned short* __restrict__ Wt = Wb + (size_t)o0 * 512;
  const unsigned short* __restrict__ Xt = X + (size_t)t0 * 512;

  f32x4 acc[4][4];
#pragma unroll
  for (int mt = 0; mt < 4; ++mt)
#pragma unroll
    for (int nt = 0; nt < 4; ++nt) acc[mt][nt] = (f32x4){0.f, 0.f, 0.f, 0.f};

  stage128x64(Wt, 512, &As[0][0], tid);
  stage128x64(Xt, 512, &Bs[0][0], tid);
  __syncthreads();

  int buf = 0;
  for (int k0 = 0; k0 < 512; k0 += 64) {
    if (k0 + 64 < 512) {
      stage128x64(Wt + k0 + 64, 512, &As[buf ^ 1][0], tid);
      stage128x64(Xt + k0 + 64, 512, &Bs[buf ^ 1][0], tid);
    }
    const char* Ab = (const char*)&As[buf][0];
    const char* Bb = (const char*)&Bs[buf][0];
    bf16x8 af[4][2], bfr[4][2];
#pragma unroll
    for (int mt = 0; mt < 4; ++mt)
#pragma unroll
      for (int kk = 0; kk < 2; ++kk) {
        const int row = wr * 64 + mt * 16 + ln;
        const int c16 = ((kk << 2) | g16) ^ (ln & 7);
        af[mt][kk] = *(const bf16x8*)(Ab + row * 128 + (c16 << 4));
      }
#pragma unroll
    for (int nt = 0; nt < 4; ++nt)
#pragma unroll
      for (int kk = 0; kk < 2; ++kk) {
        const int row = wc * 64 + nt * 16 + ln;
        const int c16 = ((kk << 2) | g16) ^ (ln & 7);
        bfr[nt][kk] = *(const bf16x8*)(Bb + row * 128 + (c16 << 4));
      }
#pragma unroll
    for (int kk = 0; kk < 2; ++kk)
#pragma unroll
      for (int mt = 0; mt < 4; ++mt)
#pragma unroll
        for (int nt = 0; nt < 4; ++nt)
          acc[mt][nt] =
              __builtin_amdgcn_mfma_f32_16x16x32_bf16(af[mt][kk], bfr[nt][kk], acc[mt][nt], 0, 0, 0);
    __syncthreads();
    buf ^= 1;
  }

  const int o_base = o0 + wr * 64, t_base = t0 + wc * 64;
#pragma unroll
  for (int mt = 0; mt < 4; ++mt) {
    const int ob16 = o_base + mt * 16;
    const int part = (ob16 >> 6) % 3;
    const int hh = ob16 / 192;
    const int c16 = ob16 & 63;
    const int bh = b * 8 + hh;
    float bv[4];
#pragma unroll
    for (int r = 0; r < 4; ++r) bv[r] = bias[ob16 + g16 * 4 + r];
#pragma unroll
    for (int nt = 0; nt < 4; ++nt) {
      const int t = t_base + nt * 16 + ln;
      float v0 = acc[mt][nt][0] + bv[0];
      float v1 = acc[mt][nt][1] + bv[1];
      float v2 = acc[mt][nt][2] + bv[2];
      float v3 = acc[mt][nt][3] + bv[3];
      if (part == 0) { v0 *= 0.125f; v1 *= 0.125f; v2 *= 0.125f; v3 *= 0.125f; }
      if (part < 2) {
        unsigned short* dst = (part == 0 ? q_t : k_t) + (size_t)bh * 65536 + (size_t)t * 64 +
                              c16 + g16 * 4;
        uint2 pk;
        pk.x = (unsigned int)f2bf(v0) | ((unsigned int)f2bf(v1) << 16);
        pk.y = (unsigned int)f2bf(v2) | ((unsigned int)f2bf(v3) << 16);
        *(uint2*)dst = pk;
      } else {
        unsigned short* dst = v_t + (size_t)bh * 65536 + (size_t)(c16 + g16 * 4) * Tn + t;
        dst[0] = f2bf(v0);
        dst[1024] = f2bf(v1);
        dst[2048] = f2bf(v2);
        dst[3072] = f2bf(v3);
      }
    }
  }
}

// ---------------------------------------------------------------------------
// Flash attention: flat grid 512, XCD-swizzled so all 8 t-chunks of a head
// share an XCD. K/V tiles LDS-staged (shared by 4 waves), double-buffered,
// XOR-swizzled. Q pre-scaled by 1/8. Defer-max softmax (THR=8).
// ---------------------------------------------------------------------------
__global__ __launch_bounds__(256, 2) void attn_kernel(const unsigned short* __restrict__ q_t,
                                                      const unsigned short* __restrict__ k_t,
                                                      const unsigned short* __restrict__ v_t,
                                                      unsigned short* __restrict__ h_t) {
  __shared__ unsigned short Ks[2][4096];
  __shared__ unsigned short Vs[2][4096];
  __shared__ unsigned short P_lds[4][32][72];
  const int id = blockIdx.x;
  const int bh = ((id >> 6) << 3) | (id & 7);
  const int tc = (id >> 3) & 7;
  const int tid = threadIdx.x, lane = tid & 63, w = tid >> 6;
  const int t_wave = tc * 128 + w * 32;
  const int ln = lane & 15, g16 = lane >> 4, g8 = g16 * 8;
  const unsigned short* __restrict__ qbase = q_t + (size_t)bh * 65536;
  const unsigned short* __restrict__ kbase = k_t + (size_t)bh * 65536;
  const unsigned short* __restrict__ vbase = v_t + (size_t)bh * 65536;

  bf16x8 qf[2][2];
#pragma unroll
  for (int mt = 0; mt < 2; ++mt)
#pragma unroll
    for (int kb = 0; kb < 2; ++kb)
      qf[mt][kb] = *(const bf16x8*)(qbase + (size_t)(t_wave + mt * 16 + ln) * 64 + kb * 32 + g8);

  f32x4 o_acc[2][4];
  float m_run[2][4], l_run[2][4];
#pragma unroll
  for (int mt = 0; mt < 2; ++mt) {
#pragma unroll
    for (int nc = 0; nc < 4; ++nc) o_acc[mt][nc] = (f32x4){0.f, 0.f, 0.f, 0.f};
#pragma unroll
    for (int r = 0; r < 4; ++r) { m_run[mt][r] = -1e30f; l_run[mt][r] = 0.f; }
  }

  stage64x64(kbase, 64, &Ks[0][0], tid);
  stage64x64(vbase, 1024, &Vs[0][0], tid);
  __syncthreads();

  int buf = 0;
  for (int st = 0; st < 16; ++st) {
    if (st < 15) {
      const int s0n = (st + 1) << 6;
      stage64x64(kbase + (size_t)s0n * 64, 64, &Ks[buf ^ 1][0], tid);
      stage64x64(vbase + s0n, 1024, &Vs[buf ^ 1][0], tid);
    }
    const char* Kb = (const char*)&Ks[buf][0];
    const char* Vb = (const char*)&Vs[buf][0];

    f32x4 sacc[2][4];
#pragma unroll
    for (int mt = 0; mt < 2; ++mt)
#pragma unroll
      for (int ns = 0; ns < 4; ++ns) sacc[mt][ns] = (f32x4){0.f, 0.f, 0.f, 0.f};

#pragma unroll
    for (int ns = 0; ns < 4; ++ns)
#pragma unroll
      for (int kb = 0; kb < 2; ++kb) {
        const int row = ns * 16 + ln;
        const int c16 = ((kb << 2) | g16) ^ (ln & 7);
        const bf16x8 kf = *(const bf16x8*)(Kb + row * 128 + (c16 << 4));
        sacc[0][ns] = __builtin_amdgcn_mfma_f32_16x16x32_bf16(qf[0][kb], kf, sacc[0][ns], 0, 0, 0);
        sacc[1][ns] = __builtin_amdgcn_mfma_f32_16x16x32_bf16(qf[1][kb], kf, sacc[1][ns], 0, 0, 0);
      }

    // row max (s already includes the 1/8 scale via q)
    float mx[2][4];
    bool need = false;
#pragma unroll
    for (int mt = 0; mt < 2; ++mt)
#pragma unroll
      for (int r = 0; r < 4; ++r) {
        float m = fmaxf(fmaxf(sacc[mt][0][r], sacc[mt][1][r]),
                        fmaxf(sacc[mt][2][r], sacc[mt][3][r]));
        m = fmaxf(m, __shfl_xor(m, 1));
        m = fmaxf(m, __shfl_xor(m, 2));
        m = fmaxf(m, __shfl_xor(m, 4));
        m = fmaxf(m, __shfl_xor(m, 8));
        mx[mt][r] = m;
        need = need || (m > m_run[mt][r] + 8.f);
      }
    if (__any(need ? 1 : 0)) {
#pragma unroll
      for (int mt = 0; mt < 2; ++mt)
#pragma unroll
        for (int r = 0; r < 4; ++r) {
          const float mnew = fmaxf(m_run[mt][r], mx[mt][r]);
          const float al = __expf(m_run[mt][r] - mnew);
          m_run[mt][r] = mnew;
          l_run[mt][r] *= al;
#pragma unroll
          for (int nc = 0; nc < 4; ++nc) o_acc[mt][nc][r] *= al;
        }
    }

#pragma unroll
    for (int mt = 0; mt < 2; ++mt)
#pragma unroll
      for (int r = 0; r < 4; ++r) {
        const int trow = mt * 16 + g16 * 4 + r;
        const float mref = m_run[mt][r];
        float rsum = 0.f;
#pragma unroll
        for (int ns = 0; ns < 4; ++ns) {
          const float pv = __expf(sacc[mt][ns][r] - mref);
          rsum += pv;
          P_lds[w][trow][ns * 16 + ln] = f2bf(pv);
        }
        rsum += __shfl_xor(rsum, 1);
        rsum += __shfl_xor(rsum, 2);
        rsum += __shfl_xor(rsum, 4);
        rsum += __shfl_xor(rsum, 8);
        l_run[mt][r] += rsum;
      }

    bf16x8 pf[2][2];
#pragma unroll
    for (int mt = 0; mt < 2; ++mt)
#pragma unroll
      for (int kb = 0; kb < 2; ++kb)
        pf[mt][kb] = *(const bf16x8*)&P_lds[w][mt * 16 + ln][kb * 32 + g8];

#pragma unroll
    for (int kb = 0; kb < 2; ++kb)
#pragma unroll
      for (int nc = 0; nc < 4; ++nc) {
        const int row = nc * 16 + ln;
        const int c16 = ((kb << 2) | g16) ^ (ln & 7);
        const bf16x8 vf = *(const bf16x8*)(Vb + row * 128 + (c16 << 4));
        o_acc[0][nc] = __builtin_amdgcn_mfma_f32_16x16x32_bf16(pf[0][kb], vf, o_acc[0][nc], 0, 0, 0);
        o_acc[1][nc] = __builtin_amdgcn_mfma_f32_16x16x32_bf16(pf[1][kb], vf, o_acc[1][nc], 0, 0, 0);
      }
    __syncthreads();
    buf ^= 1;
  }

  const int b = bh >> 3, hh = bh & 7;
  unsigned short* __restrict__ hb = h_t + (size_t)b * Tn * Cn + hh * 64;
#pragma unroll
  for (int mt = 0; mt < 2; ++mt) {
    float rl[4];
#pragma unroll
    for (int r = 0; r < 4; ++r) rl[r] = 1.f / l_run[mt][r];
#pragma unroll
    for (int nc = 0; nc < 4; ++nc) {
      const int c = nc * 16 + ln;
#pragma unroll
      for (int r = 0; r < 4; ++r) {
        const int t = t_wave + mt * 16 + g16 * 4 + r;
        hb[(size_t)t * Cn + c] = f2bf(o_acc[mt][nc][r] * rl[r]);
      }
    }
  }
}

// ---------------------------------------------------------------------------
// Proj GEMM + bias + residual, LDS-staged. Flat grid 256, XCD-swizzled.
// ---------------------------------------------------------------------------
__global__ __launch_bounds__(256, 2) void proj_gemm(const unsigned short* __restrict__ Wb,
                                                    const unsigned short* __restrict__ Hb,
                                                    const float* __restrict__ pbias,
                                                    const float* __restrict__ x,
                                                    float* __restrict__ out) {
  __shared__ unsigned short As[2][8192];
  __shared__ unsigned short Bs[2][8192];
  const int id = blockIdx.x;
  const int b = id & 7;
  const int inner = id >> 3;            // 0..31
  const int bx = inner & 3, by = inner >> 2;
  const int o0 = bx * 128, t0 = by * 128;
  const int tid = threadIdx.x, lane = tid & 63, w = tid >> 6;
  const int wr = w >> 1, wc = w & 1;
  const int ln = lane & 15, g16 = lane >> 4;
  const unsigned short* __restrict__ H = Hb + (size_t)b * Tn * Cn;
  const unsigned short* __restrict__ Wt = Wb + (size_t)o0 * 512;
  const unsigned short* __restrict__ Ht = H + (size_t)t0 * 512;

  f32x4 acc[4][4];
#pragma unroll
  for (int mt = 0; mt < 4; ++mt)
#pragma unroll
    for (int nt = 0; nt < 4; ++nt) acc[mt][nt] = (f32x4){0.f, 0.f, 0.f, 0.f};

  stage128x64(Wt, 512, &As[0][0], tid);
  stage128x64(Ht, 512, &Bs[0][0], tid);
  __syncthreads();

  int buf = 0;
  for (int k0 = 0; k0 < 512; k0 += 64) {
    if (k0 + 64 < 512) {
      stage128x64(Wt + k0 + 64, 512, &As[buf ^ 1][0], tid);
      stage128x64(Ht + k0 + 64, 512, &Bs[buf ^ 1][0], tid);
    }
    const char* Ab = (const char*)&As[buf][0];
    const char* Bb = (const char*)&Bs[buf][0];
    bf16x8 af[4][2], bfr[4][2];
#pragma unroll
    for (int mt = 0; mt < 4; ++mt)
#pragma unroll
      for (int kk = 0; kk < 2; ++kk) {
        const int row = wr * 64 + mt * 16 + ln;
        const int c16 = ((kk << 2) | g16) ^ (ln & 7);
        af[mt][kk] = *(const bf16x8*)(Ab + row * 128 + (c16 << 4));
      }
#pragma unroll
    for (int nt = 0; nt < 4; ++nt)
#pragma unroll
      for (int kk = 0; kk < 2; ++kk) {
        const int row = wc * 64 + nt * 16 + ln;
        const int c16 = ((kk << 2) | g16) ^ (ln & 7);
        bfr[nt][kk] = *(const bf16x8*)(Bb + row * 128 + (c16 << 4));
      }
#pragma unroll
    for (int kk = 0; kk < 2; ++kk)
#pragma unroll
      for (int mt = 0; mt < 4; ++mt)
#pragma unroll
        for (int nt = 0; nt < 4; ++nt)
          acc[mt][nt] =
              __builtin_amdgcn_mfma_f32_16x16x32_bf16(af[mt][kk], bfr[nt][kk], acc[mt][nt], 0, 0, 0);
    __syncthreads();
    buf ^= 1;
  }

  const int o_base = o0 + wr * 64, t_base = t0 + wc * 64;
#pragma unroll
  for (int mt = 0; mt < 4; ++mt) {
    const int ob = o_base + mt * 16 + g16 * 4;
    float pb[4];
#pragma unroll
    for (int r = 0; r < 4; ++r) pb[r] = pbias[ob + r];
#pragma unroll
    for (int nt = 0; nt < 4; ++nt) {
      const int t = t_base + nt * 16 + ln;
#pragma unroll
      for (int r = 0; r < 4; ++r) {
        const size_t idx = (size_t)b * Cn * Tn + (size_t)(ob + r) * Tn + t;
        out[idx] = acc[mt][nt][r] + pb[r] + x[idx];
      }
    }
  }
}

// ---------------------------------------------------------------------------
extern "C" void kernel_launch(void* const* d_in, const int* in_sizes, int n_in,
                              void* d_out, int out_size, void* d_ws, size_t ws_size,
                              hipStream_t stream) {
  (void)in_sizes; (void)n_in; (void)out_size; (void)ws_size;
  const float* x = (const float*)d_in[0];
  const float* gn_w = (const float*)d_in[1];
  const float* gn_b = (const float*)d_in[2];
  const float* qkv_w = (const float*)d_in[3];
  const float* qkv_b = (const float*)d_in[4];
  const float* proj_w = (const float*)d_in[5];
  const float* proj_b = (const float*)d_in[6];
  float* out = (float*)d_out;

  unsigned short* wsu = (unsigned short*)d_ws;
  unsigned short* xn_t = wsu;                         // [8][1024][512]   8MB
  unsigned short* wqkv = xn_t + (size_t)4194304;      // [1536][512]
  unsigned short* wproj = wqkv + (size_t)786432;      // [512][512]
  unsigned short* q_t = wproj + (size_t)262144;       // [64][1024][64]
  unsigned short* k_t = q_t + (size_t)4194304;
  unsigned short* v_t = k_t + (size_t)4194304;        // [64][64][1024]
  unsigned short* h_t = v_t + (size_t)4194304;        // [8][1024][512]

  gn_kernel<<<dim3(256), 256, 0, stream>>>(x, gn_w, gn_b, xn_t);
  cvt_kernel<<<dim3(768), 256, 0, stream>>>(qkv_w, wqkv, 196608);
  cvt_kernel<<<dim3(256), 256, 0, stream>>>(proj_w, wproj, 65536);
  qkv_gemm<<<dim3(768), 256, 0, stream>>>(wqkv, xn_t, qkv_b, q_t, k_t, v_t);
  attn_kernel<<<dim3(512), 256, 0, stream>>>(q_t, k_t, v_t, h_t);
  proj_gemm<<<dim3(256), 256, 0, stream>>>(wproj, h_t, proj_b, x, out);
}